// Round 7
// baseline (173.028 us; speedup 1.0000x reference)
//
#include <hip/hip_runtime.h>
#include <math.h>

#define B_ 8
#define N_ 1024
#define D_ 512
#define H_ 4
#define ND (N_ * D_)      // 524288
#define DD (D_ * D_)      // 262144
#define NN (N_ * N_)      // 1048576

typedef _Float16 f16;
typedef f16 f16x4 __attribute__((ext_vector_type(4)));
typedef f16 f16x8 __attribute__((ext_vector_type(8)));
typedef float f32x4 __attribute__((ext_vector_type(4)));

typedef __attribute__((address_space(3))) void lds_void;
typedef __attribute__((address_space(1))) void g_void;

// =====================================================================
// 256x256 8-phase GEMM core with phase-level read-ahead (R6-proven).
// Unchanged this round.
// =====================================================================

#define MFMA8(QR, QC, AV, BV, IB)                                             \
    _Pragma("unroll")                                                         \
    for (int i_ = 0; i_ < 2; ++i_) {                                          \
        const int ii_ = (IB) + i_;                                            \
        _Pragma("unroll")                                                     \
        for (int j_ = 0; j_ < 2; ++j_) {                                      \
            acc[(QR)*4+ii_][(QC)*2+j_] = __builtin_amdgcn_mfma_f32_16x16x32_f16(AV[ii_][0], BV[j_][0], acc[(QR)*4+ii_][(QC)*2+j_], 0, 0, 0); \
            acc[(QR)*4+ii_][(QC)*2+j_] = __builtin_amdgcn_mfma_f32_16x16x32_f16(AV[ii_][1], BV[j_][1], acc[(QR)*4+ii_][(QC)*2+j_], 0, 0, 0); \
        }                                                                     \
    }

#define READ_A(AV, PA, HALF)                                                  \
    _Pragma("unroll")                                                         \
    for (int i_ = 0; i_ < 4; ++i_) {                                          \
        const int ra_ = (HALF) * 128 + wr * 64 + i_ * 16 + fr;                \
        AV[i_][0] = *(const f16x8*)(PA + ra_ * 64 + sw0 * 8);                 \
        AV[i_][1] = *(const f16x8*)(PA + ra_ * 64 + sw1 * 8);                 \
    }

#define READ_B(BV, PB, HALF)                                                  \
    _Pragma("unroll")                                                         \
    for (int j_ = 0; j_ < 2; ++j_) {                                          \
        const int rb_ = (HALF) * 128 + wc * 32 + j_ * 16 + fr;                \
        BV[j_][0] = *(const f16x8*)(PB + rb_ * 64 + sw0 * 8);                 \
        BV[j_][1] = *(const f16x8*)(PB + rb_ * 64 + sw1 * 8);                 \
    }

#define PHASE_RA(QR, QC, AV, BV, READS, STAGE, TAIL)                          \
    __builtin_amdgcn_s_barrier();                                             \
    asm volatile("s_waitcnt lgkmcnt(0)" ::: "memory");                        \
    __builtin_amdgcn_sched_barrier(0);                                        \
    __builtin_amdgcn_s_setprio(1);                                            \
    MFMA8(QR, QC, AV, BV, 0);                                                 \
    __builtin_amdgcn_s_setprio(0);                                            \
    __builtin_amdgcn_sched_barrier(0);                                        \
    READS;                                                                    \
    __builtin_amdgcn_sched_barrier(0);                                        \
    STAGE;                                                                    \
    __builtin_amdgcn_s_setprio(1);                                            \
    MFMA8(QR, QC, AV, BV, 2);                                                 \
    __builtin_amdgcn_s_setprio(0);                                            \
    TAIL;

template<int LDA, int LDB, int LDC, int KTOT>
__device__ __forceinline__ void gemm256(
    const f16* __restrict__ A, const f16* __restrict__ B,
    f16* __restrict__ C, float scale, int m0, int n0)
{
    constexpr int NT = KTOT / 64;
    static_assert(NT >= 2 && (NT % 2) == 0, "NT must be even");
    __shared__ f16 sA0[256 * 64];
    __shared__ f16 sB0[256 * 64];
    __shared__ f16 sA1[256 * 64];
    __shared__ f16 sB1[256 * 64];

    const int t = threadIdx.x;
    const int w = t >> 6, l = t & 63;
    const int fr = l & 15, fq = l >> 4;     // MFMA fragment row / k-chunk
    const int wr = w >> 2, wc = w & 3;      // wave row-group / col-group
    const int lr = l >> 3, lc = l & 7;      // stage window row / chunk
    const int swc = lc ^ lr;                // pre-swizzled SOURCE chunk
    const int sw0 = fq ^ (fr & 7);          // read swizzle, ks=0
    const int sw1 = (4 + fq) ^ (fr & 7);    // read swizzle, ks=1

    f32x4 acc[8][4] = {};

    auto stageA = [&](f16* buf, int half, int kt) {
#pragma unroll
        for (int i = 0; i < 2; ++i) {
            const int r0 = half * 128 + i * 64 + w * 8;
            const f16* g = A + (size_t)(m0 + r0 + lr) * LDA + kt * 64 + swc * 8;
            __builtin_amdgcn_global_load_lds((g_void*)g, (lds_void*)(buf + r0 * 64), 16, 0, 0);
        }
    };
    auto stageB = [&](f16* buf, int half, int kt) {
#pragma unroll
        for (int i = 0; i < 2; ++i) {
            const int r0 = half * 128 + i * 64 + w * 8;
            const f16* g = B + (size_t)(n0 + r0 + lr) * LDB + kt * 64 + swc * 8;
            __builtin_amdgcn_global_load_lds((g_void*)g, (lds_void*)(buf + r0 * 64), 16, 0, 0);
        }
    };

    // prologue: tile0 fully + tile1 A0,B0 = 12 loads; drain tile0.
    stageA(sA0, 0, 0); stageB(sB0, 0, 0);
    stageA(sA0, 1, 0); stageB(sB0, 1, 0);
    stageA(sA1, 0, 1); stageB(sB1, 0, 1);
    asm volatile("s_waitcnt vmcnt(4)" ::: "memory");
    __builtin_amdgcn_s_barrier();

    f16x8 X[4][2], Y[4][2], U[2][2], V[2][2];
    READ_A(X, sA0, 0);
    READ_B(U, sB0, 0);

#define TAILCNT(KT)                                                           \
    { if ((KT) + 2 < NT) { asm volatile("s_waitcnt vmcnt(4)" ::: "memory"); } \
      else               { asm volatile("s_waitcnt vmcnt(0)" ::: "memory"); } }

#pragma unroll
    for (int tt = 0; tt < NT / 2; ++tt) {
        const int te = 2 * tt, to = 2 * tt + 1;
        // ---- even tile te: bufs sA0/sB0; A0->X, B0->U live ----
        PHASE_RA(0, 0, X, U, { READ_B(V, sB0, 1); },
                 { if (te + 1 < NT) stageA(sA1, 1, te + 1); }, {});
        PHASE_RA(0, 1, X, V, { READ_A(Y, sA0, 1); },
                 { if (te + 1 < NT) stageB(sB1, 1, te + 1); }, {});
        PHASE_RA(1, 1, Y, V, {},
                 { if (te + 2 < NT) stageA(sA0, 0, te + 2); }, {});
        PHASE_RA(1, 0, Y, U,
                 { if (te + 1 < NT) { READ_A(X, sA1, 0); READ_B(V, sB1, 0); } },
                 { if (te + 2 < NT) stageB(sB0, 0, te + 2); }, TAILCNT(te));
        // ---- odd tile to: bufs sA1/sB1; A0'->X, B0'->V live ----
        PHASE_RA(0, 0, X, V, { READ_B(U, sB1, 1); },
                 { if (to + 1 < NT) stageA(sA0, 1, to + 1); }, {});
        PHASE_RA(0, 1, X, U, { READ_A(Y, sA1, 1); },
                 { if (to + 1 < NT) stageB(sB0, 1, to + 1); }, {});
        PHASE_RA(1, 1, Y, U, {},
                 { if (to + 2 < NT) stageA(sA1, 0, to + 2); }, {});
        PHASE_RA(1, 0, Y, V,
                 { if (to + 1 < NT) { READ_A(X, sA0, 0); READ_B(U, sB0, 0); } },
                 { if (to + 2 < NT) stageB(sB1, 0, to + 2); }, TAILCNT(to));
    }
#undef TAILCNT

    // epilogue: interleaved mapping -> global C
#pragma unroll
    for (int ri = 0; ri < 8; ++ri)
#pragma unroll
        for (int cj = 0; cj < 4; ++cj)
#pragma unroll
            for (int rr = 0; rr < 4; ++rr) {
                const int row = m0 + (ri >> 2) * 128 + wr * 64 + (ri & 3) * 16 + fq * 4 + rr;
                const int col = n0 + (cj >> 1) * 128 + wc * 32 + (cj & 1) * 16 + fr;
                C[(size_t)row * LDC + col] = (f16)(acc[ri][cj][rr] * scale);
            }
}

// =====================================================================
// R0-proven 128x128 single-tile core, f32 output (final GEMM).
// =====================================================================
template<int LDA, int LDB, int LDC, int KTOT>
__device__ __forceinline__ void single_core_f32(
    const f16* __restrict__ A, const f16* __restrict__ B0,
    float* __restrict__ C, int n0, int c0)
{
    __shared__ f16 sA[128 * 32];
    __shared__ f16 sB0[128 * 32];

    const int t = threadIdx.x;
    const int w = t >> 6;
    const int l = t & 63;
    const int lrow = l >> 2;
    const int lch  = l & 3;
    const int wr = w >> 1, wc = w & 1;
    const int fr = l & 15;
    const int fq = l >> 4;

    f32x4 acc[4][4] = {};

    for (int k0 = 0; k0 < KTOT; k0 += 32) {
#pragma unroll
        for (int i = 0; i < 2; ++i) {
            const int rb  = w * 2 + i;
            const int row = rb * 16 + lrow;
            const f16* ga = A + (size_t)(n0 + row) * LDA + k0 + lch * 8;
            __builtin_amdgcn_global_load_lds((g_void*)ga, (lds_void*)(sA + rb * 512), 16, 0, 0);
            const f16* gb0 = B0 + (size_t)(c0 + row) * LDB + k0 + lch * 8;
            __builtin_amdgcn_global_load_lds((g_void*)gb0, (lds_void*)(sB0 + rb * 512), 16, 0, 0);
        }
        __syncthreads();

        f16x8 a[4], b0[4];
#pragma unroll
        for (int i = 0; i < 4; ++i) {
            a[i]  = *(const f16x8*)(sA  + (wr * 64 + i * 16 + fr) * 32 + fq * 8);
            b0[i] = *(const f16x8*)(sB0 + (wc * 64 + i * 16 + fr) * 32 + fq * 8);
        }

#pragma unroll
        for (int i = 0; i < 4; ++i)
#pragma unroll
            for (int j = 0; j < 4; ++j)
                acc[i][j] = __builtin_amdgcn_mfma_f32_16x16x32_f16(a[i], b0[j], acc[i][j], 0, 0, 0);
        __syncthreads();
    }

#pragma unroll
    for (int i = 0; i < 4; ++i)
#pragma unroll
        for (int j = 0; j < 4; ++j)
#pragma unroll
            for (int r = 0; r < 4; ++r) {
                const int row = n0 + wr * 64 + i * 16 + fq * 4 + r;
                const int col = c0 + wc * 64 + j * 16 + fr;
                C[(size_t)row * LDC + col] = acc[i][j][r];
            }
}

// GEMM1: Yh[z] = f16( x[b] @ Wh[h] ), z=b*4+h. xcd=b. 256 blocks.
__global__ __launch_bounds__(512, 2) void k_g1(
    const f16* __restrict__ xfh, const f16* __restrict__ wTh,
    f16* __restrict__ Yh)
{
    const int i = blockIdx.x;
    const int b = i & 7;
    const int li = i >> 3;            // 0..31
    const int h = li >> 3;
    const int tile = li & 7;
    const int m0 = (tile >> 1) * 256;
    const int n0 = (tile & 1) * 256;
    const int z = b * 4 + h;
    gemm256<D_, D_, D_, D_>(
        xfh + (size_t)b * ND,
        wTh + (size_t)h * DD,
        Yh + (size_t)z * ND, 1.0f, m0, n0);
}

// GEMM2: S[z] = f16( Yh[z] @ xh[b]^T * scale ). xcd=b.
// DIAGNOSTIC SPLIT: two 256-block dispatches (libase 0/1) so g2 stops
// monopolizing the top-5 counter slots; total work identical.
__global__ __launch_bounds__(512, 2) void k_g2(
    const f16* __restrict__ Yh, const f16* __restrict__ xfh,
    f16* __restrict__ S, int libase)
{
    const int i = blockIdx.x;
    const int b = i & 7;
    const int li = (i >> 3) + libase * 32;   // 0..63 across both launches
    const int h = li >> 4;
    const int tile = li & 15;
    const int m0 = (tile >> 2) * 256;
    const int n0 = (tile & 3) * 256;
    const int z = b * 4 + h;
    gemm256<D_, D_, N_, D_>(
        Yh + (size_t)z * ND,
        xfh + (size_t)b * ND,
        S + (size_t)z * NN, 0.044194173824159216f, m0, n0);
}

// Softmax + head-mean: Pbar[b] = 0.25 * sum_h softmax(S[b*4+h]).
// All 8 row-loads hoisted ahead of the reduce chains (parallel issue).
// 2048 blocks, one wave per row.
__global__ __launch_bounds__(256) void softmax_mean(
    const f16* __restrict__ S, f16* __restrict__ Pb)
{
    const int wave = threadIdx.x >> 6;
    const int l = threadIdx.x & 63;
    const int i = blockIdx.x;
    const int b = i & 7;
    const int rg = i >> 3;            // 0..255
    const int row = rg * 4 + wave;    // 0..1023

    f16x8 va[4][2];
#pragma unroll
    for (int h = 0; h < 4; ++h) {
        const f16x8* p = (const f16x8*)(S + ((size_t)(b * 4 + h) * N_ + row) * N_);
        va[h][0] = p[l * 2];
        va[h][1] = p[l * 2 + 1];
    }

    float o[16];
#pragma unroll
    for (int k = 0; k < 16; ++k) o[k] = 0.f;

#pragma unroll
    for (int h = 0; h < 4; ++h) {
        float f[16];
#pragma unroll
        for (int k = 0; k < 8; ++k) { f[k] = (float)va[h][0][k]; f[k + 8] = (float)va[h][1][k]; }
        float m = f[0];
#pragma unroll
        for (int k = 1; k < 16; ++k) m = fmaxf(m, f[k]);
#pragma unroll
        for (int off = 32; off > 0; off >>= 1) m = fmaxf(m, __shfl_xor(m, off));
        float s = 0.f;
#pragma unroll
        for (int k = 0; k < 16; ++k) { f[k] = __expf(f[k] - m); s += f[k]; }
#pragma unroll
        for (int off = 32; off > 0; off >>= 1) s += __shfl_xor(s, off);
        const float q = 0.25f / s;
#pragma unroll
        for (int k = 0; k < 16; ++k) o[k] += f[k] * q;
    }

    f16x8 o0, o1;
#pragma unroll
    for (int k = 0; k < 8; ++k) { o0[k] = (f16)o[k]; o1[k] = (f16)o[k + 8]; }
    f16x8* qp = (f16x8*)(Pb + ((size_t)b * N_ + row) * N_);
    qp[l * 2] = o0;
    qp[l * 2 + 1] = o1;
}

// Final GEMM: out[b] = Pbar[b] @ xT[b]^T, f32 direct. 256 blocks.
__global__ __launch_bounds__(256, 2) void k_g4b(
    const f16* __restrict__ Pb, const f16* __restrict__ xT,
    float* __restrict__ out)
{
    const int i = blockIdx.x;
    const int b = i & 7;
    const int li = i >> 3;            // 0..31
    const int m0 = (li >> 2) * 128;   // 8 m-tiles
    const int d0 = (li & 3) * 128;    // 4 n-tiles
    single_core_f32<N_, N_, D_, N_>(
        Pb + (size_t)b * NN,
        xT + (size_t)b * ND,
        out + (size_t)b * ND, m0, d0);
}

// Merged decomp, VECTORIZED (G13): float4 global reads, f16x4 writes,
// pad 65->68 for 8/16B alignment. Conversions identical to scalar path.
__global__ __launch_bounds__(256) void decomp_xw(
    const float* __restrict__ x, const float* __restrict__ W,
    f16* __restrict__ xfh, f16* __restrict__ xT, f16* __restrict__ wTh)
{
    __shared__ f16 tile[64][68];
    __shared__ float tw[64][68];
    const int t = threadIdx.x;
    const int z = blockIdx.z;
    if (z < 8) {
        const int b = z, n0 = blockIdx.y * 64, d0 = blockIdx.x * 64;
        const float* xb = x + (size_t)b * ND;
#pragma unroll
        for (int p = 0; p < 4; ++p) {
            const int vid = t + p * 256;       // 0..1023
            const int r = vid >> 4, c4 = vid & 15;
            const float4 v = *(const float4*)(xb + (size_t)(n0 + r) * D_ + d0 + c4 * 4);
            f16x4 hv;
            hv[0] = (f16)v.x; hv[1] = (f16)v.y; hv[2] = (f16)v.z; hv[3] = (f16)v.w;
            *(f16x4*)(xfh + (size_t)b * ND + (size_t)(n0 + r) * D_ + d0 + c4 * 4) = hv;
            *(f16x4*)(&tile[r][c4 * 4]) = hv;
        }
        __syncthreads();
#pragma unroll
        for (int p = 0; p < 4; ++p) {
            const int vid = t + p * 256;
            const int r = vid >> 4, c4 = vid & 15;
            f16x4 hv;
#pragma unroll
            for (int j = 0; j < 4; ++j) hv[j] = tile[c4 * 4 + j][r];
            *(f16x4*)(xT + (size_t)b * ND + (size_t)(d0 + r) * N_ + n0 + c4 * 4) = hv;
        }
    } else {
        if (blockIdx.y >= 8) return;
        const int h = z - 8, d0 = blockIdx.y * 64, e0 = blockIdx.x * 64;
        const float* Wh = W + (size_t)h * DD;
#pragma unroll
        for (int p = 0; p < 4; ++p) {
            const int vid = t + p * 256;
            const int r = vid >> 4, c4 = vid & 15;
            const float4 v = *(const float4*)(Wh + (size_t)(d0 + r) * D_ + e0 + c4 * 4);
            *(float4*)(&tw[r][c4 * 4]) = v;
        }
        __syncthreads();
#pragma unroll
        for (int p = 0; p < 4; ++p) {
            const int vid = t + p * 256;
            const int r = vid >> 4, c4 = vid & 15;
            f16x4 hv;
#pragma unroll
            for (int j = 0; j < 4; ++j) hv[j] = (f16)tw[c4 * 4 + j][r];
            *(f16x4*)(wTh + (size_t)h * DD + (size_t)(e0 + r) * D_ + d0 + c4 * 4) = hv;
        }
    }
}

extern "C" void kernel_launch(void* const* d_in, const int* in_sizes, int n_in,
                              void* d_out, int out_size, void* d_ws, size_t ws_size,
                              hipStream_t stream) {
    const float* x = (const float*)d_in[0];   // [8,1024,512]
    const float* W = (const float*)d_in[1];   // [4,512,512]
    float* out = (float*)d_out;               // [8,1024,512]

    // workspace layout
    char* ws = (char*)d_ws;
    const size_t MB = 1024 * 1024;
    f16*   xfh = (f16*)(ws + 0 * MB);     // 8 MiB
    f16*   xT  = (f16*)(ws + 8 * MB);     // 8 MiB
    f16*   wTh = (f16*)(ws + 16 * MB);    // 2 MiB
    f16*   Yh  = (f16*)(ws + 20 * MB);    // 32 MiB (full batch, 32 z)
    f16*   S   = (f16*)(ws + 52 * MB);    // 64 MiB (full batch, f16)
    f16*   Pb  = (f16*)(ws + 116 * MB);   // 16 MiB (head-mean P, 8 b)

    decomp_xw<<<dim3(8, 16, 12), 256, 0, stream>>>(x, W, xfh, xT, wTh);

    k_g1<<<dim3(256), 512, 0, stream>>>(xfh, wTh, Yh);
    k_g2<<<dim3(256), 512, 0, stream>>>(Yh, xfh, S, 0);
    k_g2<<<dim3(256), 512, 0, stream>>>(Yh, xfh, S, 1);
    softmax_mean<<<dim3(2048), 256, 0, stream>>>(S, Pb);
    k_g4b<<<dim3(256), 256, 0, stream>>>(Pb, xT, out);
}

// Round 8
// 168.050 us; speedup vs baseline: 1.0296x; 1.0296x over previous
//
#include <hip/hip_runtime.h>
#include <math.h>

#define B_ 8
#define N_ 1024
#define D_ 512
#define H_ 4
#define ND (N_ * D_)      // 524288
#define DD (D_ * D_)      // 262144
#define NN (N_ * N_)      // 1048576

typedef _Float16 f16;
typedef f16 f16x4 __attribute__((ext_vector_type(4)));
typedef f16 f16x8 __attribute__((ext_vector_type(8)));
typedef float f32x4 __attribute__((ext_vector_type(4)));

typedef __attribute__((address_space(3))) void lds_void;
typedef __attribute__((address_space(1))) void g_void;

// =====================================================================
// 256x256 8-phase GEMM core with phase-level read-ahead (R6-proven).
// =====================================================================

#define MFMA8(QR, QC, AV, BV, IB)                                             \
    _Pragma("unroll")                                                         \
    for (int i_ = 0; i_ < 2; ++i_) {                                          \
        const int ii_ = (IB) + i_;                                            \
        _Pragma("unroll")                                                     \
        for (int j_ = 0; j_ < 2; ++j_) {                                      \
            acc[(QR)*4+ii_][(QC)*2+j_] = __builtin_amdgcn_mfma_f32_16x16x32_f16(AV[ii_][0], BV[j_][0], acc[(QR)*4+ii_][(QC)*2+j_], 0, 0, 0); \
            acc[(QR)*4+ii_][(QC)*2+j_] = __builtin_amdgcn_mfma_f32_16x16x32_f16(AV[ii_][1], BV[j_][1], acc[(QR)*4+ii_][(QC)*2+j_], 0, 0, 0); \
        }                                                                     \
    }

#define READ_A(AV, PA, HALF)                                                  \
    _Pragma("unroll")                                                         \
    for (int i_ = 0; i_ < 4; ++i_) {                                          \
        const int ra_ = (HALF) * 128 + wr * 64 + i_ * 16 + fr;                \
        AV[i_][0] = *(const f16x8*)(PA + ra_ * 64 + sw0 * 8);                 \
        AV[i_][1] = *(const f16x8*)(PA + ra_ * 64 + sw1 * 8);                 \
    }

#define READ_B(BV, PB, HALF)                                                  \
    _Pragma("unroll")                                                         \
    for (int j_ = 0; j_ < 2; ++j_) {                                          \
        const int rb_ = (HALF) * 128 + wc * 32 + j_ * 16 + fr;                \
        BV[j_][0] = *(const f16x8*)(PB + rb_ * 64 + sw0 * 8);                 \
        BV[j_][1] = *(const f16x8*)(PB + rb_ * 64 + sw1 * 8);                 \
    }

#define PHASE_RA(QR, QC, AV, BV, READS, STAGE, TAIL)                          \
    __builtin_amdgcn_s_barrier();                                             \
    asm volatile("s_waitcnt lgkmcnt(0)" ::: "memory");                        \
    __builtin_amdgcn_sched_barrier(0);                                        \
    __builtin_amdgcn_s_setprio(1);                                            \
    MFMA8(QR, QC, AV, BV, 0);                                                 \
    __builtin_amdgcn_s_setprio(0);                                            \
    __builtin_amdgcn_sched_barrier(0);                                        \
    READS;                                                                    \
    __builtin_amdgcn_sched_barrier(0);                                        \
    STAGE;                                                                    \
    __builtin_amdgcn_s_setprio(1);                                            \
    MFMA8(QR, QC, AV, BV, 2);                                                 \
    __builtin_amdgcn_s_setprio(0);                                            \
    TAIL;

template<int LDA, int LDB, int LDC, int KTOT>
__device__ __forceinline__ void gemm256(
    const f16* __restrict__ A, const f16* __restrict__ B,
    f16* __restrict__ C, float scale, int m0, int n0)
{
    constexpr int NT = KTOT / 64;
    static_assert(NT >= 2 && (NT % 2) == 0, "NT must be even");
    __shared__ f16 sA0[256 * 64];
    __shared__ f16 sB0[256 * 64];
    __shared__ f16 sA1[256 * 64];
    __shared__ f16 sB1[256 * 64];

    const int t = threadIdx.x;
    const int w = t >> 6, l = t & 63;
    const int fr = l & 15, fq = l >> 4;
    const int wr = w >> 2, wc = w & 3;
    const int lr = l >> 3, lc = l & 7;
    const int swc = lc ^ lr;
    const int sw0 = fq ^ (fr & 7);
    const int sw1 = (4 + fq) ^ (fr & 7);

    f32x4 acc[8][4] = {};

    auto stageA = [&](f16* buf, int half, int kt) {
#pragma unroll
        for (int i = 0; i < 2; ++i) {
            const int r0 = half * 128 + i * 64 + w * 8;
            const f16* g = A + (size_t)(m0 + r0 + lr) * LDA + kt * 64 + swc * 8;
            __builtin_amdgcn_global_load_lds((g_void*)g, (lds_void*)(buf + r0 * 64), 16, 0, 0);
        }
    };
    auto stageB = [&](f16* buf, int half, int kt) {
#pragma unroll
        for (int i = 0; i < 2; ++i) {
            const int r0 = half * 128 + i * 64 + w * 8;
            const f16* g = B + (size_t)(n0 + r0 + lr) * LDB + kt * 64 + swc * 8;
            __builtin_amdgcn_global_load_lds((g_void*)g, (lds_void*)(buf + r0 * 64), 16, 0, 0);
        }
    };

    stageA(sA0, 0, 0); stageB(sB0, 0, 0);
    stageA(sA0, 1, 0); stageB(sB0, 1, 0);
    stageA(sA1, 0, 1); stageB(sB1, 0, 1);
    asm volatile("s_waitcnt vmcnt(4)" ::: "memory");
    __builtin_amdgcn_s_barrier();

    f16x8 X[4][2], Y[4][2], U[2][2], V[2][2];
    READ_A(X, sA0, 0);
    READ_B(U, sB0, 0);

#define TAILCNT(KT)                                                           \
    { if ((KT) + 2 < NT) { asm volatile("s_waitcnt vmcnt(4)" ::: "memory"); } \
      else               { asm volatile("s_waitcnt vmcnt(0)" ::: "memory"); } }

#pragma unroll
    for (int tt = 0; tt < NT / 2; ++tt) {
        const int te = 2 * tt, to = 2 * tt + 1;
        PHASE_RA(0, 0, X, U, { READ_B(V, sB0, 1); },
                 { if (te + 1 < NT) stageA(sA1, 1, te + 1); }, {});
        PHASE_RA(0, 1, X, V, { READ_A(Y, sA0, 1); },
                 { if (te + 1 < NT) stageB(sB1, 1, te + 1); }, {});
        PHASE_RA(1, 1, Y, V, {},
                 { if (te + 2 < NT) stageA(sA0, 0, te + 2); }, {});
        PHASE_RA(1, 0, Y, U,
                 { if (te + 1 < NT) { READ_A(X, sA1, 0); READ_B(V, sB1, 0); } },
                 { if (te + 2 < NT) stageB(sB0, 0, te + 2); }, TAILCNT(te));
        PHASE_RA(0, 0, X, V, { READ_B(U, sB1, 1); },
                 { if (to + 1 < NT) stageA(sA0, 1, to + 1); }, {});
        PHASE_RA(0, 1, X, U, { READ_A(Y, sA1, 1); },
                 { if (to + 1 < NT) stageB(sB0, 1, to + 1); }, {});
        PHASE_RA(1, 1, Y, U, {},
                 { if (to + 2 < NT) stageA(sA1, 0, to + 2); }, {});
        PHASE_RA(1, 0, Y, V,
                 { if (to + 1 < NT) { READ_A(X, sA0, 0); READ_B(U, sB0, 0); } },
                 { if (to + 2 < NT) stageB(sB1, 0, to + 2); }, TAILCNT(to));
    }
#undef TAILCNT

#pragma unroll
    for (int ri = 0; ri < 8; ++ri)
#pragma unroll
        for (int cj = 0; cj < 4; ++cj)
#pragma unroll
            for (int rr = 0; rr < 4; ++rr) {
                const int row = m0 + (ri >> 2) * 128 + wr * 64 + (ri & 3) * 16 + fq * 4 + rr;
                const int col = n0 + (cj >> 1) * 128 + wc * 32 + (cj & 1) * 16 + fr;
                C[(size_t)row * LDC + col] = (f16)(acc[ri][cj][rr] * scale);
            }
}

// GEMM1: Yh[z] = f16( x[b] @ Wh[h] ), z=b*4+h. xcd=b. 256 blocks.
__global__ __launch_bounds__(512, 2) void k_g1(
    const f16* __restrict__ xfh, const f16* __restrict__ wTh,
    f16* __restrict__ Yh)
{
    const int i = blockIdx.x;
    const int b = i & 7;
    const int li = i >> 3;
    const int h = li >> 3;
    const int tile = li & 7;
    const int m0 = (tile >> 1) * 256;
    const int n0 = (tile & 1) * 256;
    const int z = b * 4 + h;
    gemm256<D_, D_, D_, D_>(
        xfh + (size_t)b * ND,
        wTh + (size_t)h * DD,
        Yh + (size_t)z * ND, 1.0f, m0, n0);
}

// GEMM2: S[z] = f16( Yh[z] @ xh[b]^T * scale ). xcd=b. 512 blocks (merged).
__global__ __launch_bounds__(512, 2) void k_g2(
    const f16* __restrict__ Yh, const f16* __restrict__ xfh,
    f16* __restrict__ S)
{
    const int i = blockIdx.x;
    const int b = i & 7;
    const int li = i >> 3;
    const int h = li >> 4;
    const int tile = li & 15;
    const int m0 = (tile >> 2) * 256;
    const int n0 = (tile & 3) * 256;
    const int z = b * 4 + h;
    gemm256<D_, D_, N_, D_>(
        Yh + (size_t)z * ND,
        xfh + (size_t)b * ND,
        S + (size_t)z * NN, 0.044194173824159216f, m0, n0);
}

// =====================================================================
// FUSED softmax+head-mean+PV: out[b] rows r0..r0+31 =
//   ( 0.25 * sum_h softmax(S[b*4+h]) ) @ x[b],  f32 direct to output.
// Kills the Pbar HBM round-trip (32 MB) and one launch.
// 256 blocks (b = i&7 XCD-aligned, 32 row-tiles), 512 threads = 8 waves.
// Phase 1: per-wave-row softmax (proven softmax_mean math, identical
//   order) -> Pbar tile [32][1024] f16 in LDS, chunk-swizzled c^(row&7).
// Phase 2: PV GEMM, K=1024 in 32-wide chunks; xT chunk [512][32] LDS
//   double-buffered via global_load_lds with pre-swizzled source chunk
//   kc^((d>>1)&3) (rule #21). Fragment maps copied from gemm256.
// =====================================================================
__global__ __launch_bounds__(512, 2) void k_smpv(
    const f16* __restrict__ S, const f16* __restrict__ xT,
    float* __restrict__ out)
{
    __shared__ f16 Pl[32 * 1024];       // 64 KiB
    __shared__ f16 Bt0[512 * 32];       // 32 KiB
    __shared__ f16 Bt1[512 * 32];       // 32 KiB

    const int t = threadIdx.x;
    const int w = t >> 6, l = t & 63;
    const int fr = l & 15, fq = l >> 4;
    const int i = blockIdx.x;
    const int b = i & 7;
    const int mt = i >> 3;              // 0..31
    const int r0 = mt * 32;
    const f16* xTb = xT + (size_t)b * ND;

    auto stage = [&](f16* buf, int it) {
#pragma unroll
        for (int j = 0; j < 4; ++j) {
            const int flat = (w * 4 + j) * 64 + l;   // 0..2047
            const int d  = flat >> 2;
            const int kc = flat & 3;
            const f16* g = xTb + (size_t)d * N_ + it * 32 + (kc ^ ((d >> 1) & 3)) * 8;
            __builtin_amdgcn_global_load_lds((g_void*)g, (lds_void*)(buf + flat * 8), 16, 0, 0);
        }
    };

    // issue first xT chunk early: overlaps with the softmax phase
    stage(Bt0, 0);

    // ---- Phase 1: softmax + head-mean, 4 rows per wave ----
#pragma unroll
    for (int rr = 0; rr < 4; ++rr) {
        const int lrw = w * 4 + rr;          // local row 0..31
        const int grow = r0 + lrw;
        f16x8 va[4][2];
#pragma unroll
        for (int h = 0; h < 4; ++h) {
            const f16x8* p = (const f16x8*)(S + ((size_t)(b * 4 + h) * N_ + grow) * N_);
            va[h][0] = p[l * 2];
            va[h][1] = p[l * 2 + 1];
        }
        float o[16];
#pragma unroll
        for (int k = 0; k < 16; ++k) o[k] = 0.f;
#pragma unroll
        for (int h = 0; h < 4; ++h) {
            float f[16];
#pragma unroll
            for (int k = 0; k < 8; ++k) { f[k] = (float)va[h][0][k]; f[k + 8] = (float)va[h][1][k]; }
            float m = f[0];
#pragma unroll
            for (int k = 1; k < 16; ++k) m = fmaxf(m, f[k]);
#pragma unroll
            for (int off = 32; off > 0; off >>= 1) m = fmaxf(m, __shfl_xor(m, off));
            float s = 0.f;
#pragma unroll
            for (int k = 0; k < 16; ++k) { f[k] = __expf(f[k] - m); s += f[k]; }
#pragma unroll
            for (int off = 32; off > 0; off >>= 1) s += __shfl_xor(s, off);
            const float q = 0.25f / s;
#pragma unroll
            for (int k = 0; k < 16; ++k) o[k] += f[k] * q;
        }
        f16x8 o0, o1;
#pragma unroll
        for (int k = 0; k < 8; ++k) { o0[k] = (f16)o[k]; o1[k] = (f16)o[k + 8]; }
        const int s0 = (2 * l)     ^ (lrw & 7);
        const int s1 = (2 * l + 1) ^ (lrw & 7);
        *(f16x8*)(Pl + lrw * 1024 + s0 * 8) = o0;
        *(f16x8*)(Pl + lrw * 1024 + s1 * 8) = o1;
    }
    __syncthreads();   // P visible; Bt0 staged (barrier drains vmcnt)

    // ---- Phase 2: PV, out[32x512] = P[32x1024] @ xT^T ----
    f32x4 acc[2][4] = {};

    auto compute = [&](const f16* buf, int it) {
        f16x8 av[2], bv[4];
#pragma unroll
        for (int mi = 0; mi < 2; ++mi) {
            const int row = mi * 16 + fr;
            const int slot = (it * 4 + fq) ^ (fr & 7);
            av[mi] = *(const f16x8*)(Pl + row * 1024 + slot * 8);
        }
#pragma unroll
        for (int nf = 0; nf < 4; ++nf) {
            const int d = w * 64 + nf * 16 + fr;
            const int slot = fq ^ ((d >> 1) & 3);
            bv[nf] = *(const f16x8*)(buf + d * 32 + slot * 8);
        }
#pragma unroll
        for (int mi = 0; mi < 2; ++mi)
#pragma unroll
            for (int nf = 0; nf < 4; ++nf)
                acc[mi][nf] = __builtin_amdgcn_mfma_f32_16x16x32_f16(av[mi], bv[nf], acc[mi][nf], 0, 0, 0);
    };

    for (int ii = 0; ii < 16; ++ii) {
        const int e = 2 * ii, od = 2 * ii + 1;
        if (e + 1 < 32) stage(Bt1, e + 1);
        compute(Bt0, e);
        __syncthreads();
        if (od + 1 < 32) stage(Bt0, od + 1);
        compute(Bt1, od);
        __syncthreads();
    }

    // epilogue: f32 direct to out[b], gemm256-proven C mapping
#pragma unroll
    for (int mi = 0; mi < 2; ++mi)
#pragma unroll
        for (int nf = 0; nf < 4; ++nf)
#pragma unroll
            for (int rr = 0; rr < 4; ++rr) {
                const int row = r0 + mi * 16 + fq * 4 + rr;
                const int col = w * 64 + nf * 16 + fr;
                out[(size_t)b * ND + (size_t)row * D_ + col] = acc[mi][nf][rr];
            }
}

// Merged decomp, vectorized (R7): float4 reads, f16x4 writes.
__global__ __launch_bounds__(256) void decomp_xw(
    const float* __restrict__ x, const float* __restrict__ W,
    f16* __restrict__ xfh, f16* __restrict__ xT, f16* __restrict__ wTh)
{
    __shared__ f16 tile[64][68];
    __shared__ float tw[64][68];
    const int t = threadIdx.x;
    const int z = blockIdx.z;
    if (z < 8) {
        const int b = z, n0 = blockIdx.y * 64, d0 = blockIdx.x * 64;
        const float* xb = x + (size_t)b * ND;
#pragma unroll
        for (int p = 0; p < 4; ++p) {
            const int vid = t + p * 256;
            const int r = vid >> 4, c4 = vid & 15;
            const float4 v = *(const float4*)(xb + (size_t)(n0 + r) * D_ + d0 + c4 * 4);
            f16x4 hv;
            hv[0] = (f16)v.x; hv[1] = (f16)v.y; hv[2] = (f16)v.z; hv[3] = (f16)v.w;
            *(f16x4*)(xfh + (size_t)b * ND + (size_t)(n0 + r) * D_ + d0 + c4 * 4) = hv;
            *(f16x4*)(&tile[r][c4 * 4]) = hv;
        }
        __syncthreads();
#pragma unroll
        for (int p = 0; p < 4; ++p) {
            const int vid = t + p * 256;
            const int r = vid >> 4, c4 = vid & 15;
            f16x4 hv;
#pragma unroll
            for (int j = 0; j < 4; ++j) hv[j] = tile[c4 * 4 + j][r];
            *(f16x4*)(xT + (size_t)b * ND + (size_t)(d0 + r) * N_ + n0 + c4 * 4) = hv;
        }
    } else {
        if (blockIdx.y >= 8) return;
        const int h = z - 8, d0 = blockIdx.y * 64, e0 = blockIdx.x * 64;
        const float* Wh = W + (size_t)h * DD;
#pragma unroll
        for (int p = 0; p < 4; ++p) {
            const int vid = t + p * 256;
            const int r = vid >> 4, c4 = vid & 15;
            const float4 v = *(const float4*)(Wh + (size_t)(d0 + r) * D_ + e0 + c4 * 4);
            *(float4*)(&tw[r][c4 * 4]) = v;
        }
        __syncthreads();
#pragma unroll
        for (int p = 0; p < 4; ++p) {
            const int vid = t + p * 256;
            const int r = vid >> 4, c4 = vid & 15;
            f16x4 hv;
#pragma unroll
            for (int j = 0; j < 4; ++j) hv[j] = (f16)tw[c4 * 4 + j][r];
            *(f16x4*)(wTh + (size_t)h * DD + (size_t)(e0 + r) * D_ + d0 + c4 * 4) = hv;
        }
    }
}

extern "C" void kernel_launch(void* const* d_in, const int* in_sizes, int n_in,
                              void* d_out, int out_size, void* d_ws, size_t ws_size,
                              hipStream_t stream) {
    const float* x = (const float*)d_in[0];   // [8,1024,512]
    const float* W = (const float*)d_in[1];   // [4,512,512]
    float* out = (float*)d_out;               // [8,1024,512]

    char* ws = (char*)d_ws;
    const size_t MB = 1024 * 1024;
    f16*   xfh = (f16*)(ws + 0 * MB);     // 8 MiB
    f16*   xT  = (f16*)(ws + 8 * MB);     // 8 MiB
    f16*   wTh = (f16*)(ws + 16 * MB);    // 2 MiB
    f16*   Yh  = (f16*)(ws + 20 * MB);    // 32 MiB
    f16*   S   = (f16*)(ws + 52 * MB);    // 64 MiB

    decomp_xw<<<dim3(8, 16, 12), 256, 0, stream>>>(x, W, xfh, xT, wTh);
    k_g1<<<dim3(256), 512, 0, stream>>>(xfh, wTh, Yh);
    k_g2<<<dim3(512), 512, 0, stream>>>(Yh, xfh, S);
    k_smpv<<<dim3(256), 512, 0, stream>>>(S, xT, out);
}